// Round 3
// baseline (177.554 us; speedup 1.0000x reference)
//
#include <hip/hip_runtime.h>

#define B_DIM 4096
#define I_DIM 1024
#define O_DIM 1024
#define ON_DIM 4096   // O * N fan-in columns

typedef _Float16 half8  __attribute__((ext_vector_type(8)));
typedef _Float16 half4_t __attribute__((ext_vector_type(4)));
typedef float    floatx4 __attribute__((ext_vector_type(4)));

// ---------------------------------------------------------------------------
// Kernel 1 (fused prep):
//  blocks [0,1024):   softmax of mapping_logits rows -> fp16 weights (wave/row)
//  blocks [1024,2048): x fp32 -> fp16 convert
// Stores are NON-TEMPORAL: wh/xh are consumed by the GEMM from *other* XCDs;
// leaving dirty lines in the writer XCD's L2 forces slow cross-XCD dirty
// reads (suspected cause of R1/R2's 41 MB FETCH_SIZE vs 16 MB compulsory).
// ---------------------------------------------------------------------------
__global__ __launch_bounds__(256)
void ltn_prep(const float* __restrict__ logits, const float* __restrict__ x,
              _Float16* __restrict__ wh, _Float16* __restrict__ xh) {
  const int t = threadIdx.x, lane = t & 63, wv = t >> 6;
  if (blockIdx.x < 1024) {
    const int row = blockIdx.x * 4 + wv;
    const float4* src = (const float4*)(logits + (size_t)row * I_DIM);
    float4 v[4];
#pragma unroll
    for (int j = 0; j < 4; j++) v[j] = src[j * 64 + lane];
    float m = -1e30f;
#pragma unroll
    for (int j = 0; j < 4; j++)
      m = fmaxf(m, fmaxf(fmaxf(v[j].x, v[j].y), fmaxf(v[j].z, v[j].w)));
#pragma unroll
    for (int off = 1; off < 64; off <<= 1) m = fmaxf(m, __shfl_xor(m, off));
    float e[16];
    float s = 0.0f;
#pragma unroll
    for (int j = 0; j < 4; j++) {
      e[4 * j + 0] = __expf(v[j].x - m);
      e[4 * j + 1] = __expf(v[j].y - m);
      e[4 * j + 2] = __expf(v[j].z - m);
      e[4 * j + 3] = __expf(v[j].w - m);
      s += (e[4 * j + 0] + e[4 * j + 1]) + (e[4 * j + 2] + e[4 * j + 3]);
    }
#pragma unroll
    for (int off = 1; off < 64; off <<= 1) s += __shfl_xor(s, off);
    const float inv = 1.0f / s;
    half4_t* dst = (half4_t*)(wh + (size_t)row * I_DIM);
#pragma unroll
    for (int j = 0; j < 4; j++) {
      half4_t h;
      h[0] = (_Float16)(e[4 * j + 0] * inv);
      h[1] = (_Float16)(e[4 * j + 1] * inv);
      h[2] = (_Float16)(e[4 * j + 2] * inv);
      h[3] = (_Float16)(e[4 * j + 3] * inv);
      __builtin_nontemporal_store(h, &dst[j * 64 + lane]);
    }
  } else {
    const int cidx = blockIdx.x - 1024;
    const float4* src = (const float4*)x;
    half4_t* dst = (half4_t*)xh;
#pragma unroll
    for (int j = 0; j < 4; j++) {
      const int idx = cidx * 1024 + j * 256 + t;
      const float4 v = src[idx];
      half4_t h;
      h[0] = (_Float16)v.x; h[1] = (_Float16)v.y;
      h[2] = (_Float16)v.z; h[3] = (_Float16)v.w;
      __builtin_nontemporal_store(h, &dst[idx]);
    }
  }
}

// ---------------------------------------------------------------------------
// Kernel 2: fused GEMM (selected = x @ w^T) + sigmoid + 16-corner LUT interp.
// 128x128 block tile, BK=32 (BK=64 regressed: R2). Double-buffered LDS with
// prefetch-before-compute: next tile's global_load_lds issues at the top of
// the iteration, so the end-of-compute barrier drains a load that had the
// whole compute phase in flight. 8x8 supertile swizzle keeps each group's
// working set (2MB A + 2MB B) within one XCD L2.
// ---------------------------------------------------------------------------
__global__ __launch_bounds__(256)
void ltn_gemm_lut(const _Float16* __restrict__ xh,   // [B][I]
                  const _Float16* __restrict__ wh,   // [ON][I]
                  const float* __restrict__ lut,     // [O][16]
                  float* __restrict__ out) {         // [B][O]
  __shared__ _Float16 As[2][4][128][8];   // 2 x 8 KB
  __shared__ _Float16 Bs[2][4][128][8];   // 2 x 8 KB

  const int tid  = threadIdx.x;
  const int lane = tid & 63;
  const int wv   = tid >> 6;     // wave 0..3
  const int wr   = wv >> 1;      // wave row (0..1)
  const int wc   = wv & 1;       // wave col (0..1)

  // 8x8 supertile swizzle over the 32x32 tile grid
  const int id     = blockIdx.x;
  const int st     = id >> 6;          // 16 supertiles, 4x4 arrangement
  const int within = id & 63;
  const int tm = (st & 3) * 8 + (within & 7);
  const int tn = (st >> 2) * 8 + (within >> 3);
  const int bm0 = tm * 128;
  const int bn0 = tn * 128;

  const int fm = lane & 15;      // m/n within a 16-tile
  const int kq = lane >> 4;      // quad -> k-block index (k = kq*8 + j)

  floatx4 acc[4][4];
#pragma unroll
  for (int i = 0; i < 4; i++)
#pragma unroll
    for (int j = 0; j < 4; j++) acc[i][j] = (floatx4)0.0f;

  // stage one 128x32 tile pair into buffer `buf` (8 GLL issues per block)
  auto stage = [&](int buf, int k0) {
#pragma unroll
    for (int s = 0; s < 2; s++) {
      const int ci0 = (wv * 2 + s) * 64;          // wave-uniform
      const int ci  = ci0 + lane;
      const int m   = ci & 127;
      const int kb  = ci >> 7;
      const _Float16* gA = xh + (size_t)(bm0 + m) * I_DIM + k0 + kb * 8;
      const _Float16* gB = wh + (size_t)(bn0 + m) * I_DIM + k0 + kb * 8;
      __builtin_amdgcn_global_load_lds(
          (const __attribute__((address_space(1))) void*)gA,
          (__attribute__((address_space(3))) void*)(&As[buf][0][0][0] + ci0 * 8),
          16, 0, 0);
      __builtin_amdgcn_global_load_lds(
          (const __attribute__((address_space(1))) void*)gB,
          (__attribute__((address_space(3))) void*)(&Bs[buf][0][0][0] + ci0 * 8),
          16, 0, 0);
    }
  };

  auto compute = [&](int buf) {
    half8 af[4], bf[4];
#pragma unroll
    for (int f = 0; f < 4; f++) {
      af[f] = *(const half8*)&As[buf][kq][wr * 64 + f * 16 + fm][0];
      bf[f] = *(const half8*)&Bs[buf][kq][wc * 64 + f * 16 + fm][0];
    }
#pragma unroll
    for (int mt = 0; mt < 4; mt++)
#pragma unroll
      for (int nt = 0; nt < 4; nt++)
        acc[mt][nt] = __builtin_amdgcn_mfma_f32_16x16x32_f16(
            af[mt], bf[nt], acc[mt][nt], 0, 0, 0);
  };

  stage(0, 0);
  __syncthreads();                       // initial fill (unavoidable drain)
  // unrolled by 2 so buffer indices are compile-time constants
  for (int k0 = 0; k0 < I_DIM; k0 += 64) {
    stage(1, k0 + 32);                   // prefetch (k0+32 <= 992 always)
    compute(0);
    __syncthreads();                     // drains prefetch after compute
    if (k0 + 64 < I_DIM) stage(0, k0 + 64);
    compute(1);
    __syncthreads();
  }

  // ---- fused epilogue: sigmoid -> gather 4 fan-in values -> LUT contraction
  // C/D layout: col = lane&15, row = (lane>>4)*4 + reg. The 4 n-values of one
  // o live in 4 consecutive lanes (same row, cols o*4..o*4+3).
#pragma unroll
  for (int nt = 0; nt < 4; nt++) {
    const int o = (bn0 + wc * 64 + nt * 16 + (lane & 15)) >> 2;
    const float4* lt4 = (const float4*)(lut + (size_t)o * 16);
    const float4 L0 = lt4[0], L1 = lt4[1], L2 = lt4[2], L3 = lt4[3];
#pragma unroll
    for (int mt = 0; mt < 4; mt++) {
#pragma unroll
      for (int r = 0; r < 4; r++) {
        const float v  = acc[mt][nt][r];
        const float sv = 1.0f / (1.0f + __expf(-v));
        const float s1 = __shfl_down(sv, 1);
        const float s2 = __shfl_down(sv, 2);
        const float s3 = __shfl_down(sv, 3);
        if ((lane & 3) == 0) {
          const float s0 = sv;
          const float a0 = L0.x + (L2.x - L0.x) * s3;
          const float a1 = L0.y + (L2.y - L0.y) * s3;
          const float a2 = L0.z + (L2.z - L0.z) * s3;
          const float a3 = L0.w + (L2.w - L0.w) * s3;
          const float a4 = L1.x + (L3.x - L1.x) * s3;
          const float a5 = L1.y + (L3.y - L1.y) * s3;
          const float a6 = L1.z + (L3.z - L1.z) * s3;
          const float a7 = L1.w + (L3.w - L1.w) * s3;
          const float b0 = a0 + (a4 - a0) * s2;
          const float b1 = a1 + (a5 - a1) * s2;
          const float b2 = a2 + (a6 - a2) * s2;
          const float b3 = a3 + (a7 - a3) * s2;
          const float c0 = b0 + (b2 - b0) * s1;
          const float c1 = b1 + (b3 - b1) * s1;
          const float res = c0 + (c1 - c0) * s0;
          const int row = bm0 + wr * 64 + mt * 16 + (lane >> 4) * 4 + r;
          out[(size_t)row * O_DIM + o] = res;
        }
      }
    }
  }
}

// ---------------------------------------------------------------------------
extern "C" void kernel_launch(void* const* d_in, const int* in_sizes, int n_in,
                              void* d_out, int out_size, void* d_ws, size_t ws_size,
                              hipStream_t stream) {
  const float* x      = (const float*)d_in[0];  // (B, I)
  const float* logits = (const float*)d_in[1];  // (O, N, I)
  const float* lut    = (const float*)d_in[2];  // (O, 16)
  float* out          = (float*)d_out;          // (B, O)

  _Float16* wh = (_Float16*)d_ws;                                  // 8 MB
  _Float16* xh = (_Float16*)d_ws + (size_t)ON_DIM * I_DIM;         // 8 MB

  ltn_prep<<<2048, 256, 0, stream>>>(logits, x, wh, xh);
  dim3 grid(1024);
  ltn_gemm_lut<<<grid, 256, 0, stream>>>(xh, wh, lut, out);
}